// Round 6
// baseline (320.594 us; speedup 1.0000x reference)
//
#include <hip/hip_runtime.h>
#include <hip/hip_cooperative_groups.h>

namespace cg = cooperative_groups;

#define NEDGE 625000
#define NNODE 50000
#define NTILES ((NEDGE + 127) / 128)   // 4883
#define NMTILES ((NNODE + 31) / 32)    // 1563
#define WPITCH 136  // edge lW pitch in shorts (64 rows x 136 = 8704)
#define EPITCH 68   // uv epilogue pitch in shorts (4*32*68 = 8704)

typedef __bf16 bf16x8 __attribute__((ext_vector_type(8)));
typedef __bf16 bf16x4 __attribute__((ext_vector_type(4)));
typedef unsigned short u16x8 __attribute__((ext_vector_type(8)));
typedef float f32x4 __attribute__((ext_vector_type(4)));
typedef float f32x8 __attribute__((ext_vector_type(8)));

__device__ __forceinline__ unsigned short f32_bf16(float f) {
  unsigned int u = __float_as_uint(f);
  u += 0x7FFFu + ((u >> 16) & 1u);  // RNE
  return (unsigned short)(u >> 16);
}

// packed bf16 add + relu; RNE bf16 add == f32-add-then-round (absmax-verified r4/r5)
__device__ __forceinline__ bf16x8 addrelu8(u16x8 ua, u16x8 ub) {
  bf16x8 a = *(bf16x8*)&ua, b = *(bf16x8*)&ub;
  bf16x8 s = a + b;
  const bf16x8 z = {(__bf16)0.f, (__bf16)0.f, (__bf16)0.f, (__bf16)0.f,
                    (__bf16)0.f, (__bf16)0.f, (__bf16)0.f, (__bf16)0.f};
  return __builtin_elementwise_max(s, z);
}

// ---------------------------------------------------------------------------
// Fused cooperative kernel: phase A (weight prep) -> grid.sync ->
// phase B (UV node GEMM) -> grid.sync -> phase C (edge gather+MLP).
// LDS: one 17408 B buffer, reused as uv-epilogue staging then as W2 tile.
// ---------------------------------------------------------------------------
__global__ __launch_bounds__(256, 4) void fused_kernel(
    const float* __restrict__ z, const int* __restrict__ ei,
    const float* __restrict__ W1, const float* __restrict__ b1,
    const float* __restrict__ W2, const float* __restrict__ b2,
    const float* __restrict__ W3, const float* __restrict__ b3,
    unsigned short* __restrict__ UV, unsigned short* __restrict__ WcatT,
    unsigned short* __restrict__ W2T, float* __restrict__ out)
{
  __shared__ unsigned short smem[8704];
  cg::grid_group grid = cg::this_grid();
  const int t = threadIdx.x, wave = t >> 6, lane = t & 63, c = lane & 15, q = lane >> 4;

  // ---- phase A: WcatT[j'][k] = W1 transposed-concat, W2T[n][k] = W2^T (bf16) ----
  for (int i = blockIdx.x * 256 + t; i < 256 * 128 + 64 * 128; i += gridDim.x * 256) {
    if (i < 256 * 128) {
      int jp = i >> 7, k = i & 127;
      float v = (jp < 128) ? W1[k * 128 + jp] : W1[(128 + k) * 128 + (jp - 128)];
      WcatT[jp * 128 + k] = f32_bf16(v);
    } else {
      int i2 = i - 256 * 128;
      int n = i2 >> 7, k = i2 & 127;
      W2T[n * 128 + k] = f32_bf16(W2[k * 64 + n]);
    }
  }
  grid.sync();

  // ---- phase B: UV[n][0:128] = z@W1_top + b1 ; UV[n][128:256] = z@W1_bot ----
  // 32 rows per mtile; wave w handles column-chunk nc=w. Barrier-free per tile.
  for (int mtile = blockIdx.x; mtile < NMTILES; mtile += gridDim.x) {
    const int nc = wave;
    const int mbase = mtile * 32;
    const int rA = mbase + c, rB = mbase + 16 + c;
    const int rAc = (rA < NNODE) ? rA : 0;
    const int rBc = (rB < NNODE) ? rB : 0;

    bf16x8 a0[4], a1[4];
    {
      const float* zA = z + (size_t)rAc * 128 + q * 8;
      const float* zB = z + (size_t)rBc * 128 + q * 8;
#pragma unroll
      for (int kt = 0; kt < 4; ++kt) {
        f32x8 vA = *(const f32x8*)(zA + kt * 32);
        f32x8 vB = *(const f32x8*)(zB + kt * 32);
        a0[kt] = __builtin_convertvector(vA, bf16x8);
        a1[kt] = __builtin_convertvector(vB, bf16x8);
      }
    }

    f32x4 acc[2][4];
#pragma unroll
    for (int mt = 0; mt < 2; ++mt)
#pragma unroll
      for (int nt = 0; nt < 4; ++nt) {
        f32x4 zz = {0.f, 0.f, 0.f, 0.f};
        acc[mt][nt] = zz;
      }

#pragma unroll
    for (int kt = 0; kt < 4; ++kt) {
#pragma unroll
      for (int nt = 0; nt < 4; ++nt) {
        bf16x8 bb = *(const bf16x8*)(WcatT + (size_t)(nc * 64 + nt * 16 + c) * 128 + kt * 32 + q * 8);
        acc[0][nt] = __builtin_amdgcn_mfma_f32_16x16x32_bf16(a0[kt], bb, acc[0][nt], 0, 0, 0);
        acc[1][nt] = __builtin_amdgcn_mfma_f32_16x16x32_bf16(a1[kt], bb, acc[1][nt], 0, 0, 0);
      }
    }

    float badd[4];
#pragma unroll
    for (int nt = 0; nt < 4; ++nt) {
      int col = nc * 64 + nt * 16 + c;
      badd[nt] = (col < 128) ? b1[col] : 0.f;
    }

    unsigned short* my = &smem[wave * 32 * EPITCH];
#pragma unroll
    for (int mt = 0; mt < 2; ++mt)
#pragma unroll
      for (int nt = 0; nt < 4; ++nt) {
        f32x4 v = acc[mt][nt];
        f32x4 vb = {v[0] + badd[nt], v[1] + badd[nt], v[2] + badd[nt], v[3] + badd[nt]};
        bf16x4 bv = __builtin_convertvector(vb, bf16x4);
        const unsigned short* pv = (const unsigned short*)&bv;
#pragma unroll
        for (int reg = 0; reg < 4; ++reg)
          my[(mt * 16 + q * 4 + reg) * EPITCH + nt * 16 + c] = pv[reg];
      }
    __asm__ volatile("s_waitcnt lgkmcnt(0)" ::: "memory");

    {  // lane -> (row, half): 32 shorts (64 B) vectorized store
      int lrow = lane >> 1, half = lane & 1;
      int grow = mbase + lrow;
      u16x8 d0 = *(u16x8*)&my[lrow * EPITCH + half * 32 + 0];
      u16x8 d1 = *(u16x8*)&my[lrow * EPITCH + half * 32 + 8];
      u16x8 d2 = *(u16x8*)&my[lrow * EPITCH + half * 32 + 16];
      u16x8 d3 = *(u16x8*)&my[lrow * EPITCH + half * 32 + 24];
      if (grow < NNODE) {
        u16x8* dst = (u16x8*)(UV + (size_t)grow * 256 + nc * 64 + half * 32);
        dst[0] = d0; dst[1] = d1; dst[2] = d2; dst[3] = d3;
      }
    }
    __asm__ volatile("s_waitcnt lgkmcnt(0)" ::: "memory");  // LDS reads drain before next tile overwrites
  }
  grid.sync();

  // ---- phase C: edge gather + layer2 MFMA + fp32 epilogue ----
  {  // stage W2T once per block (reused across ~NTILES/grid tiles)
    int n = t >> 2, qd = t & 3;
    const u16x8* src = (const u16x8*)(W2T + n * 128 + qd * 32);
    u16x8* dst = (u16x8*)(&smem[n * WPITCH + qd * 32]);
#pragma unroll
    for (int i = 0; i < 4; ++i) dst[i] = src[i];
  }
  __syncthreads();

  int is64;
  {
    int allz = 1;
    for (int j = 1; j < 64; j += 2) allz &= (ei[j] == 0);
    is64 = allz;  // int64 edge_index -> odd 32-bit words are zero
  }

  float b2v[4], w3v[4];
#pragma unroll
  for (int nt = 0; nt < 4; ++nt) {
    int n = nt * 16 + c;
    b2v[nt] = b2[n];
    w3v[nt] = W3[n];
  }
  const float bias3 = b3[0];

  for (int tile = blockIdx.x; tile < NTILES; tile += gridDim.x) {
    const int ebase = tile * 128 + wave * 32;
    const int eA = ebase + c, eB = ebase + 16 + c;
    const int eAc = (eA < NEDGE) ? eA : 0;
    const int eBc = (eB < NEDGE) ? eB : 0;
    int sA, dA, sB, dB;
    if (is64) {
      const long long* e64 = (const long long*)ei;
      sA = (int)e64[eAc]; dA = (int)e64[NEDGE + eAc];
      sB = (int)e64[eBc]; dB = (int)e64[NEDGE + eBc];
    } else {
      sA = ei[eAc]; dA = ei[NEDGE + eAc];
      sB = ei[eBc]; dB = ei[NEDGE + eBc];
    }

    const u16x8* pAu = (const u16x8*)(UV + (size_t)sA * 256) + q;
    const u16x8* pAv = (const u16x8*)(UV + (size_t)dA * 256 + 128) + q;
    const u16x8* pBu = (const u16x8*)(UV + (size_t)sB * 256) + q;
    const u16x8* pBv = (const u16x8*)(UV + (size_t)dB * 256 + 128) + q;
    u16x8 rAu[4], rAv[4], rBu[4], rBv[4];
#pragma unroll
    for (int kt = 0; kt < 4; ++kt) {
      rAu[kt] = pAu[kt * 4];
      rAv[kt] = pAv[kt * 4];
      rBu[kt] = pBu[kt * 4];
      rBv[kt] = pBv[kt * 4];
    }

    f32x4 acc[2][4];
#pragma unroll
    for (int mt = 0; mt < 2; ++mt)
#pragma unroll
      for (int nt = 0; nt < 4; ++nt) {
        f32x4 zz = {0.f, 0.f, 0.f, 0.f};
        acc[mt][nt] = zz;
      }

#pragma unroll
    for (int kt = 0; kt < 4; ++kt) {
      bf16x8 a0 = addrelu8(rAu[kt], rAv[kt]);
      bf16x8 a1 = addrelu8(rBu[kt], rBv[kt]);
#pragma unroll
      for (int nt = 0; nt < 4; ++nt) {
        bf16x8 bb = *(const bf16x8*)(&smem[(nt * 16 + c) * WPITCH + kt * 32 + q * 8]);
        acc[0][nt] = __builtin_amdgcn_mfma_f32_16x16x32_bf16(a0, bb, acc[0][nt], 0, 0, 0);
        acc[1][nt] = __builtin_amdgcn_mfma_f32_16x16x32_bf16(a1, bb, acc[1][nt], 0, 0, 0);
      }
    }

#pragma unroll
    for (int mt = 0; mt < 2; ++mt) {
      float p0 = 0.f, p1 = 0.f, p2 = 0.f, p3 = 0.f;
#pragma unroll
      for (int nt = 0; nt < 4; ++nt) {
        p0 += fmaxf(acc[mt][nt][0] + b2v[nt], 0.f) * w3v[nt];
        p1 += fmaxf(acc[mt][nt][1] + b2v[nt], 0.f) * w3v[nt];
        p2 += fmaxf(acc[mt][nt][2] + b2v[nt], 0.f) * w3v[nt];
        p3 += fmaxf(acc[mt][nt][3] + b2v[nt], 0.f) * w3v[nt];
      }
#pragma unroll
      for (int m = 1; m < 16; m <<= 1) {
        p0 += __shfl_xor(p0, m, 64);
        p1 += __shfl_xor(p1, m, 64);
        p2 += __shfl_xor(p2, m, 64);
        p3 += __shfl_xor(p3, m, 64);
      }
      if (c == 0) {
        int eb = ebase + mt * 16 + q * 4;
        if (eb + 0 < NEDGE) out[eb + 0] = p0 + bias3;
        if (eb + 1 < NEDGE) out[eb + 1] = p1 + bias3;
        if (eb + 2 < NEDGE) out[eb + 2] = p2 + bias3;
        if (eb + 3 < NEDGE) out[eb + 3] = p3 + bias3;
      }
    }
  }
}

extern "C" void kernel_launch(void* const* d_in, const int* in_sizes, int n_in,
                              void* d_out, int out_size, void* d_ws, size_t ws_size,
                              hipStream_t stream) {
  const float* z  = (const float*)d_in[0];
  const int*   ei = (const int*)d_in[1];
  const float* W1 = (const float*)d_in[2];
  const float* b1 = (const float*)d_in[3];
  const float* W2 = (const float*)d_in[4];
  const float* b2 = (const float*)d_in[5];
  const float* W3 = (const float*)d_in[6];
  const float* b3 = (const float*)d_in[7];
  float* out = (float*)d_out;

  unsigned short* UV    = (unsigned short*)d_ws;       // 50000*256 bf16 = 25.6 MB
  unsigned short* WcatT = UV + (size_t)NNODE * 256;    // 256*128 bf16
  unsigned short* W2T   = WcatT + 256 * 128;           // 64*128 bf16

  int maxB = 0;
  hipOccupancyMaxActiveBlocksPerMultiprocessor(&maxB, (const void*)fused_kernel, 256, 0);
  if (maxB < 1) maxB = 1;
  if (maxB > 4) maxB = 4;
  int grid = maxB * 256;

  void* args[] = {(void*)&z, (void*)&ei, (void*)&W1, (void*)&b1,
                  (void*)&W2, (void*)&b2, (void*)&W3, (void*)&b3,
                  (void*)&UV, (void*)&WcatT, (void*)&W2T, (void*)&out};
  hipLaunchCooperativeKernel((const void*)fused_kernel, dim3(grid), dim3(256),
                             args, 0, stream);
}

// Round 7
// 310.862 us; speedup vs baseline: 1.0313x; 1.0313x over previous
//
#include <hip/hip_runtime.h>

#define NEDGE 625000
#define NNODE 50000
#define NTILES ((NEDGE + 127) / 128)   // 4883
#define EGRID 2048                     // persistent edge grid: 8 blocks/CU x 256 CU
#define WPITCH 136  // lW pitch in shorts: 272 B rows -> 2-way bank aliasing on b128 (free)
#define ZPITCH 136  // uv z-stage pitch in shorts
#define EPITCH 68   // uv epilogue pitch in shorts

typedef __bf16 bf16x8 __attribute__((ext_vector_type(8)));
typedef __bf16 bf16x4 __attribute__((ext_vector_type(4)));
typedef unsigned short u16x8 __attribute__((ext_vector_type(8)));
typedef float f32x4 __attribute__((ext_vector_type(4)));
typedef float f32x8 __attribute__((ext_vector_type(8)));

__device__ __forceinline__ unsigned short f32_bf16(float f) {
  unsigned int u = __float_as_uint(f);
  u += 0x7FFFu + ((u >> 16) & 1u);  // RNE
  return (unsigned short)(u >> 16);
}

// packed bf16 add + relu; RNE bf16 add == f32-add-then-round (absmax-verified r4/r5)
__device__ __forceinline__ bf16x8 addrelu8(u16x8 ua, u16x8 ub) {
  bf16x8 a = *(bf16x8*)&ua, b = *(bf16x8*)&ub;
  bf16x8 s = a + b;
  const bf16x8 z = {(__bf16)0.f, (__bf16)0.f, (__bf16)0.f, (__bf16)0.f,
                    (__bf16)0.f, (__bf16)0.f, (__bf16)0.f, (__bf16)0.f};
  return __builtin_elementwise_max(s, z);
}

// ---------------------------------------------------------------------------
// prep: WcatT[j'][k] = W1[k][j'] (j'<128) | W1[128+k][j'-128], bf16
//       W2T[n][k]    = W2[k][n], bf16; idx64_flag from odd-word probe
// ---------------------------------------------------------------------------
__global__ __launch_bounds__(256) void prep_kernel(
    const float* __restrict__ W1, const float* __restrict__ W2,
    const int* __restrict__ ei,
    unsigned short* __restrict__ WcatT, unsigned short* __restrict__ W2T,
    int* __restrict__ idx64_flag)
{
  int i = blockIdx.x * 256 + threadIdx.x;
  if (i < 256 * 128) {
    int jp = i >> 7, k = i & 127;
    float v = (jp < 128) ? W1[k * 128 + jp] : W1[(128 + k) * 128 + (jp - 128)];
    WcatT[jp * 128 + k] = f32_bf16(v);
  } else if (i < 256 * 128 + 64 * 128) {
    int i2 = i - 256 * 128;
    int n = i2 >> 7, k = i2 & 127;
    W2T[n * 128 + k] = f32_bf16(W2[k * 64 + n]);
  }
  if (i == 0) {
    int allz = 1;
    for (int j = 1; j < 64; j += 2) allz &= (ei[j] == 0);
    *idx64_flag = allz;
  }
}

// ---------------------------------------------------------------------------
// uv: UV[n][0:128] = z@W1_top + b1, UV[n][128:256] = z@W1_bot  (bf16)
// z tile (32 rows) staged ONCE in LDS as bf16 (z read exactly once from HBM);
// wave w computes column-chunk nc=w. B-frags from L2-hot WcatT.
// ---------------------------------------------------------------------------
__global__ __launch_bounds__(256) void uv_kernel(
    const float* __restrict__ z, const float* __restrict__ b1,
    const unsigned short* __restrict__ WcatT,
    unsigned short* __restrict__ UV)
{
  __shared__ unsigned short zb[32 * ZPITCH];        // 8704 B: staged z tile (bf16)
  __shared__ unsigned short st[4 * 32 * EPITCH];    // 17408 B: epilogue transpose
  const int t = threadIdx.x, wave = t >> 6, lane = t & 63, c = lane & 15, q = lane >> 4;
  const int nc = wave;
  const int mbase = blockIdx.x * 32;

  {  // stage z: thread t -> row t>>3, 16-float chunk t&7; cvt to bf16
    int r = t >> 3, ch = t & 7;
    int grow = mbase + r;
    const float* src = z + (size_t)((grow < NNODE) ? grow : 0) * 128 + ch * 16;
    f32x8 f0 = ((const f32x8*)src)[0];
    f32x8 f1 = ((const f32x8*)src)[1];
    bf16x8 b0 = __builtin_convertvector(f0, bf16x8);
    bf16x8 b1 = __builtin_convertvector(f1, bf16x8);
    unsigned short* d = &zb[r * ZPITCH + ch * 16];
    *(bf16x8*)(d + 0) = b0;
    *(bf16x8*)(d + 8) = b1;
  }
  __syncthreads();

  bf16x8 a0[4], a1[4];
#pragma unroll
  for (int kt = 0; kt < 4; ++kt) {
    a0[kt] = *(const bf16x8*)(&zb[c * ZPITCH + kt * 32 + q * 8]);
    a1[kt] = *(const bf16x8*)(&zb[(16 + c) * ZPITCH + kt * 32 + q * 8]);
  }

  f32x4 acc[2][4];
#pragma unroll
  for (int mt = 0; mt < 2; ++mt)
#pragma unroll
    for (int nt = 0; nt < 4; ++nt) {
      f32x4 zz = {0.f, 0.f, 0.f, 0.f};
      acc[mt][nt] = zz;
    }

#pragma unroll
  for (int kt = 0; kt < 4; ++kt) {
#pragma unroll
    for (int nt = 0; nt < 4; ++nt) {
      bf16x8 bb = *(const bf16x8*)(WcatT + (size_t)(nc * 64 + nt * 16 + c) * 128 + kt * 32 + q * 8);
      acc[0][nt] = __builtin_amdgcn_mfma_f32_16x16x32_bf16(a0[kt], bb, acc[0][nt], 0, 0, 0);
      acc[1][nt] = __builtin_amdgcn_mfma_f32_16x16x32_bf16(a1[kt], bb, acc[1][nt], 0, 0, 0);
    }
  }

  float badd[4];
#pragma unroll
  for (int nt = 0; nt < 4; ++nt) {
    int col = nc * 64 + nt * 16 + c;
    badd[nt] = (col < 128) ? b1[col] : 0.f;
  }

  unsigned short* my = &st[wave * 32 * EPITCH];
#pragma unroll
  for (int mt = 0; mt < 2; ++mt)
#pragma unroll
    for (int nt = 0; nt < 4; ++nt) {
      f32x4 v = acc[mt][nt];
      f32x4 vb = {v[0] + badd[nt], v[1] + badd[nt], v[2] + badd[nt], v[3] + badd[nt]};
      bf16x4 bv = __builtin_convertvector(vb, bf16x4);
      const unsigned short* pv = (const unsigned short*)&bv;
#pragma unroll
      for (int reg = 0; reg < 4; ++reg)
        my[(mt * 16 + q * 4 + reg) * EPITCH + nt * 16 + c] = pv[reg];
    }
  __asm__ volatile("s_waitcnt lgkmcnt(0)" ::: "memory");

  {  // lane -> (row, half): 32 shorts (64 B) vectorized store
    int lrow = lane >> 1, half = lane & 1;
    int grow = mbase + lrow;
    u16x8 d0 = *(u16x8*)&my[lrow * EPITCH + half * 32 + 0];
    u16x8 d1 = *(u16x8*)&my[lrow * EPITCH + half * 32 + 8];
    u16x8 d2 = *(u16x8*)&my[lrow * EPITCH + half * 32 + 16];
    u16x8 d3 = *(u16x8*)&my[lrow * EPITCH + half * 32 + 24];
    if (grow < NNODE) {
      u16x8* dst = (u16x8*)(UV + (size_t)grow * 256 + nc * 64 + half * 32);
      dst[0] = d0; dst[1] = d1; dst[2] = d2; dst[3] = d3;
    }
  }
}

// ---------------------------------------------------------------------------
// edge: persistent grid-stride (8 blocks/CU). W2T staged once per block;
// per tile: gather A-frags directly from UV, layer2 MFMA, fp32 epilogue.
// ---------------------------------------------------------------------------
__global__ __launch_bounds__(256, 8) void edge_kernel(
    const int* __restrict__ ei,
    const unsigned short* __restrict__ UV,
    const unsigned short* __restrict__ W2T,
    const float* __restrict__ b2, const float* __restrict__ W3,
    const float* __restrict__ b3, const int* __restrict__ idx64_flag,
    float* __restrict__ out)
{
  __shared__ unsigned short lW[64 * WPITCH];
  const int t = threadIdx.x, wave = t >> 6, lane = t & 63, c = lane & 15, q = lane >> 4;

  {  // stage W2T once per block (reused across ~2.4 tiles)
    int n = t >> 2, qd = t & 3;
    const u16x8* src = (const u16x8*)(W2T + n * 128 + qd * 32);
    u16x8* dst = (u16x8*)(&lW[n * WPITCH + qd * 32]);
#pragma unroll
    for (int i = 0; i < 4; ++i) dst[i] = src[i];
  }
  __syncthreads();  // the only barrier

  const int is64 = *idx64_flag;
  float b2v[4], w3v[4];
#pragma unroll
  for (int nt = 0; nt < 4; ++nt) {
    int n = nt * 16 + c;
    b2v[nt] = b2[n];
    w3v[nt] = W3[n];
  }
  const float bias3 = b3[0];

  for (int tile = blockIdx.x; tile < NTILES; tile += EGRID) {
    const int ebase = tile * 128 + wave * 32;
    const int eA = ebase + c, eB = ebase + 16 + c;
    const int eAc = (eA < NEDGE) ? eA : 0;
    const int eBc = (eB < NEDGE) ? eB : 0;
    int sA, dA, sB, dB;
    if (is64) {
      const long long* e64 = (const long long*)ei;
      sA = (int)e64[eAc]; dA = (int)e64[NEDGE + eAc];
      sB = (int)e64[eBc]; dB = (int)e64[NEDGE + eBc];
    } else {
      sA = ei[eAc]; dA = ei[NEDGE + eAc];
      sB = ei[eBc]; dB = ei[NEDGE + eBc];
    }

    // 16 independent 16B gather loads (4 per kt)
    const u16x8* pAu = (const u16x8*)(UV + (size_t)sA * 256) + q;
    const u16x8* pAv = (const u16x8*)(UV + (size_t)dA * 256 + 128) + q;
    const u16x8* pBu = (const u16x8*)(UV + (size_t)sB * 256) + q;
    const u16x8* pBv = (const u16x8*)(UV + (size_t)dB * 256 + 128) + q;
    u16x8 rAu[4], rAv[4], rBu[4], rBv[4];
#pragma unroll
    for (int kt = 0; kt < 4; ++kt) {
      rAu[kt] = pAu[kt * 4];
      rAv[kt] = pAv[kt * 4];
      rBu[kt] = pBu[kt * 4];
      rBv[kt] = pBv[kt * 4];
    }

    f32x4 acc[2][4];
#pragma unroll
    for (int mt = 0; mt < 2; ++mt)
#pragma unroll
      for (int nt = 0; nt < 4; ++nt) {
        f32x4 zz = {0.f, 0.f, 0.f, 0.f};
        acc[mt][nt] = zz;
      }

#pragma unroll
    for (int kt = 0; kt < 4; ++kt) {
      bf16x8 a0 = addrelu8(rAu[kt], rAv[kt]);
      bf16x8 a1 = addrelu8(rBu[kt], rBv[kt]);
#pragma unroll
      for (int nt = 0; nt < 4; ++nt) {
        bf16x8 bb = *(const bf16x8*)(&lW[(nt * 16 + c) * WPITCH + kt * 32 + q * 8]);
        acc[0][nt] = __builtin_amdgcn_mfma_f32_16x16x32_bf16(a0, bb, acc[0][nt], 0, 0, 0);
        acc[1][nt] = __builtin_amdgcn_mfma_f32_16x16x32_bf16(a1, bb, acc[1][nt], 0, 0, 0);
      }
    }

    // layer-2 bias+relu and layer-3 dot in fp32; reduce over the 16 c-lanes
#pragma unroll
    for (int mt = 0; mt < 2; ++mt) {
      float p0 = 0.f, p1 = 0.f, p2 = 0.f, p3 = 0.f;
#pragma unroll
      for (int nt = 0; nt < 4; ++nt) {
        p0 += fmaxf(acc[mt][nt][0] + b2v[nt], 0.f) * w3v[nt];
        p1 += fmaxf(acc[mt][nt][1] + b2v[nt], 0.f) * w3v[nt];
        p2 += fmaxf(acc[mt][nt][2] + b2v[nt], 0.f) * w3v[nt];
        p3 += fmaxf(acc[mt][nt][3] + b2v[nt], 0.f) * w3v[nt];
      }
#pragma unroll
      for (int m = 1; m < 16; m <<= 1) {
        p0 += __shfl_xor(p0, m, 64);
        p1 += __shfl_xor(p1, m, 64);
        p2 += __shfl_xor(p2, m, 64);
        p3 += __shfl_xor(p3, m, 64);
      }
      if (c == 0) {
        int eb = ebase + mt * 16 + q * 4;
        if (eb + 0 < NEDGE) out[eb + 0] = p0 + bias3;
        if (eb + 1 < NEDGE) out[eb + 1] = p1 + bias3;
        if (eb + 2 < NEDGE) out[eb + 2] = p2 + bias3;
        if (eb + 3 < NEDGE) out[eb + 3] = p3 + bias3;
      }
    }
  }
}

extern "C" void kernel_launch(void* const* d_in, const int* in_sizes, int n_in,
                              void* d_out, int out_size, void* d_ws, size_t ws_size,
                              hipStream_t stream) {
  const float* z  = (const float*)d_in[0];
  const int*   ei = (const int*)d_in[1];
  const float* W1 = (const float*)d_in[2];
  const float* b1 = (const float*)d_in[3];
  const float* W2 = (const float*)d_in[4];
  const float* b2 = (const float*)d_in[5];
  const float* W3 = (const float*)d_in[6];
  const float* b3 = (const float*)d_in[7];
  float* out = (float*)d_out;

  unsigned short* UV    = (unsigned short*)d_ws;       // 50000*256 bf16 = 25.6 MB
  unsigned short* WcatT = UV + (size_t)NNODE * 256;    // 256*128 bf16
  unsigned short* W2T   = WcatT + 256 * 128;           // 64*128 bf16
  int* idx64_flag       = (int*)(W2T + 64 * 128);

  prep_kernel<<<dim3(160), dim3(256), 0, stream>>>(W1, W2, ei, WcatT, W2T, idx64_flag);
  uv_kernel<<<dim3((NNODE + 31) / 32), dim3(256), 0, stream>>>(z, b1, WcatT, UV);
  edge_kernel<<<dim3(EGRID), dim3(256), 0, stream>>>(
      ei, UV, W2T, b2, W3, b3, idx64_flag, out);
}

// Round 8
// 241.546 us; speedup vs baseline: 1.3273x; 1.2870x over previous
//
#include <hip/hip_runtime.h>
#include <hip/hip_cooperative_groups.h>

namespace cg = cooperative_groups;

#define NEDGE 625000
#define NNODE 50000
#define NTILES ((NEDGE + 127) / 128)   // 4883 edge tiles
#define NMTILES ((NNODE + 31) / 32)    // 1563 node tiles
#define WPITCH 136  // edge lW pitch in shorts (64*136 = 8704 shorts)
#define ZPITCH 136  // uv z-stage pitch in shorts (32*136 = 4352 shorts)
#define EPITCH 68   // uv epilogue pitch in shorts (4*32*68 = 8704 shorts)

typedef __bf16 bf16x8 __attribute__((ext_vector_type(8)));
typedef __bf16 bf16x4 __attribute__((ext_vector_type(4)));
typedef unsigned short u16x8 __attribute__((ext_vector_type(8)));
typedef float f32x4 __attribute__((ext_vector_type(4)));
typedef float f32x8 __attribute__((ext_vector_type(8)));

__device__ __forceinline__ unsigned short f32_bf16(float f) {
  unsigned int u = __float_as_uint(f);
  u += 0x7FFFu + ((u >> 16) & 1u);  // RNE
  return (unsigned short)(u >> 16);
}

// packed bf16 add + relu; RNE bf16 add == f32-add-then-round (absmax-verified r4-r7)
__device__ __forceinline__ bf16x8 addrelu8(u16x8 ua, u16x8 ub) {
  bf16x8 a = *(bf16x8*)&ua, b = *(bf16x8*)&ub;
  bf16x8 s = a + b;
  const bf16x8 z = {(__bf16)0.f, (__bf16)0.f, (__bf16)0.f, (__bf16)0.f,
                    (__bf16)0.f, (__bf16)0.f, (__bf16)0.f, (__bf16)0.f};
  return __builtin_elementwise_max(s, z);
}

// ---------------------------------------------------------------------------
// One cooperative kernel, 3 phases:
//   A: weight prep (WcatT = [W1_top|W1_bot]^T bf16, W2T = W2^T bf16, is64 flag)
//   B: UV node GEMM (z staged once in LDS; z HBM traffic = 25.6 MB exactly)
//   C: edge gather + layer2 MFMA + fp32 epilogue (persistent grid-stride)
// NO register cap: compiler found a 52-VGPR no-spill schedule for phase C
// standalone (r5); forcing 8 waves/EU (r7) or 4 (r6) caused scratch spills.
// ---------------------------------------------------------------------------
__global__ __launch_bounds__(256) void fused_kernel(
    const float* __restrict__ z, const int* __restrict__ ei,
    const float* __restrict__ W1, const float* __restrict__ b1,
    const float* __restrict__ W2, const float* __restrict__ b2,
    const float* __restrict__ W3, const float* __restrict__ b3,
    unsigned short* __restrict__ UV, unsigned short* __restrict__ WcatT,
    unsigned short* __restrict__ W2T, int* __restrict__ idx64_flag,
    float* __restrict__ out)
{
  // 26112 B: phase B uses [zb | st]; phase C reuses the front as lW
  __shared__ unsigned short smem[13056];
  cg::grid_group grid = cg::this_grid();
  const int t = threadIdx.x, wave = t >> 6, lane = t & 63, c = lane & 15, q = lane >> 4;

  // ---- phase A ----
  for (int i = blockIdx.x * 256 + t; i < 256 * 128 + 64 * 128; i += gridDim.x * 256) {
    if (i < 256 * 128) {
      int jp = i >> 7, k = i & 127;
      float v = (jp < 128) ? W1[k * 128 + jp] : W1[(128 + k) * 128 + (jp - 128)];
      WcatT[jp * 128 + k] = f32_bf16(v);
    } else {
      int i2 = i - 256 * 128;
      int n = i2 >> 7, k = i2 & 127;
      W2T[n * 128 + k] = f32_bf16(W2[k * 64 + n]);
    }
  }
  if (blockIdx.x == 0 && t == 0) {
    int allz = 1;
    for (int j = 1; j < 64; j += 2) allz &= (ei[j] == 0);
    *idx64_flag = allz;  // int64 edge_index -> odd 32-bit words are zero
  }
  grid.sync();

  // ---- phase B: UV[n][0:128] = z@W1_top + b1 ; UV[n][128:256] = z@W1_bot ----
  {
    unsigned short* zb = smem;          // 4352 shorts
    unsigned short* st = smem + 4352;   // 8704 shorts
    const int nc = wave;
    for (int mtile = blockIdx.x; mtile < NMTILES; mtile += gridDim.x) {
      const int mbase = mtile * 32;
      {  // stage z tile once: thread t -> row t>>3, 16-float chunk t&7
        int r = t >> 3, ch = t & 7;
        int grow = mbase + r;
        const float* src = z + (size_t)((grow < NNODE) ? grow : 0) * 128 + ch * 16;
        f32x8 f0 = ((const f32x8*)src)[0];
        f32x8 f1 = ((const f32x8*)src)[1];
        bf16x8 c0 = __builtin_convertvector(f0, bf16x8);
        bf16x8 c1 = __builtin_convertvector(f1, bf16x8);
        unsigned short* d = &zb[r * ZPITCH + ch * 16];
        *(bf16x8*)(d + 0) = c0;
        *(bf16x8*)(d + 8) = c1;
      }
      __syncthreads();

      bf16x8 a0[4], a1[4];
#pragma unroll
      for (int kt = 0; kt < 4; ++kt) {
        a0[kt] = *(const bf16x8*)(&zb[c * ZPITCH + kt * 32 + q * 8]);
        a1[kt] = *(const bf16x8*)(&zb[(16 + c) * ZPITCH + kt * 32 + q * 8]);
      }

      f32x4 acc[2][4];
#pragma unroll
      for (int mt = 0; mt < 2; ++mt)
#pragma unroll
        for (int nt = 0; nt < 4; ++nt) {
          f32x4 zz = {0.f, 0.f, 0.f, 0.f};
          acc[mt][nt] = zz;
        }

#pragma unroll
      for (int kt = 0; kt < 4; ++kt) {
#pragma unroll
        for (int nt = 0; nt < 4; ++nt) {
          bf16x8 bb = *(const bf16x8*)(WcatT + (size_t)(nc * 64 + nt * 16 + c) * 128 + kt * 32 + q * 8);
          acc[0][nt] = __builtin_amdgcn_mfma_f32_16x16x32_bf16(a0[kt], bb, acc[0][nt], 0, 0, 0);
          acc[1][nt] = __builtin_amdgcn_mfma_f32_16x16x32_bf16(a1[kt], bb, acc[1][nt], 0, 0, 0);
        }
      }

      float badd[4];
#pragma unroll
      for (int nt = 0; nt < 4; ++nt) {
        int col = nc * 64 + nt * 16 + c;
        badd[nt] = (col < 128) ? b1[col] : 0.f;
      }

      unsigned short* my = &st[wave * 32 * EPITCH];
#pragma unroll
      for (int mt = 0; mt < 2; ++mt)
#pragma unroll
        for (int nt = 0; nt < 4; ++nt) {
          f32x4 v = acc[mt][nt];
          f32x4 vb = {v[0] + badd[nt], v[1] + badd[nt], v[2] + badd[nt], v[3] + badd[nt]};
          bf16x4 bv = __builtin_convertvector(vb, bf16x4);
          const unsigned short* pv = (const unsigned short*)&bv;
#pragma unroll
          for (int reg = 0; reg < 4; ++reg)
            my[(mt * 16 + q * 4 + reg) * EPITCH + nt * 16 + c] = pv[reg];
        }
      __asm__ volatile("s_waitcnt lgkmcnt(0)" ::: "memory");

      {  // lane -> (row, half): 32 shorts (64 B) vectorized store
        int lrow = lane >> 1, half = lane & 1;
        int grow = mbase + lrow;
        u16x8 d0 = *(u16x8*)&my[lrow * EPITCH + half * 32 + 0];
        u16x8 d1 = *(u16x8*)&my[lrow * EPITCH + half * 32 + 8];
        u16x8 d2 = *(u16x8*)&my[lrow * EPITCH + half * 32 + 16];
        u16x8 d3 = *(u16x8*)&my[lrow * EPITCH + half * 32 + 24];
        if (grow < NNODE) {
          u16x8* dst = (u16x8*)(UV + (size_t)grow * 256 + nc * 64 + half * 32);
          dst[0] = d0; dst[1] = d1; dst[2] = d2; dst[3] = d3;
        }
      }
      __syncthreads();  // all LDS (zb reads + st reads) done before next mtile
    }
  }
  grid.sync();

  // ---- phase C: edge gather + MLP (r5's verified 52-VGPR body) ----
  {
    unsigned short* lW = smem;  // 8704 shorts
    {  // stage W2T once per block (amortized over ~NTILES/grid tiles)
      int n = t >> 2, qd = t & 3;
      const u16x8* src = (const u16x8*)(W2T + n * 128 + qd * 32);
      u16x8* dst = (u16x8*)(&lW[n * WPITCH + qd * 32]);
#pragma unroll
      for (int i = 0; i < 4; ++i) dst[i] = src[i];
    }
    __syncthreads();

    const int is64 = *idx64_flag;
    float b2v[4], w3v[4];
#pragma unroll
    for (int nt = 0; nt < 4; ++nt) {
      int n = nt * 16 + c;
      b2v[nt] = b2[n];
      w3v[nt] = W3[n];
    }
    const float bias3 = b3[0];

    for (int tile = blockIdx.x; tile < NTILES; tile += gridDim.x) {
      const int ebase = tile * 128 + wave * 32;
      const int eA = ebase + c, eB = ebase + 16 + c;
      const int eAc = (eA < NEDGE) ? eA : 0;
      const int eBc = (eB < NEDGE) ? eB : 0;
      int sA, dA, sB, dB;
      if (is64) {
        const long long* e64 = (const long long*)ei;
        sA = (int)e64[eAc]; dA = (int)e64[NEDGE + eAc];
        sB = (int)e64[eBc]; dB = (int)e64[NEDGE + eBc];
      } else {
        sA = ei[eAc]; dA = ei[NEDGE + eAc];
        sB = ei[eBc]; dB = ei[NEDGE + eBc];
      }

      const u16x8* pAu = (const u16x8*)(UV + (size_t)sA * 256) + q;
      const u16x8* pAv = (const u16x8*)(UV + (size_t)dA * 256 + 128) + q;
      const u16x8* pBu = (const u16x8*)(UV + (size_t)sB * 256) + q;
      const u16x8* pBv = (const u16x8*)(UV + (size_t)dB * 256 + 128) + q;
      u16x8 rAu[4], rAv[4], rBu[4], rBv[4];
#pragma unroll
      for (int kt = 0; kt < 4; ++kt) {
        rAu[kt] = pAu[kt * 4];
        rAv[kt] = pAv[kt * 4];
        rBu[kt] = pBu[kt * 4];
        rBv[kt] = pBv[kt * 4];
      }

      f32x4 acc[2][4];
#pragma unroll
      for (int mt = 0; mt < 2; ++mt)
#pragma unroll
        for (int nt = 0; nt < 4; ++nt) {
          f32x4 zz = {0.f, 0.f, 0.f, 0.f};
          acc[mt][nt] = zz;
        }

#pragma unroll
      for (int kt = 0; kt < 4; ++kt) {
        bf16x8 a0 = addrelu8(rAu[kt], rAv[kt]);
        bf16x8 a1 = addrelu8(rBu[kt], rBv[kt]);
#pragma unroll
        for (int nt = 0; nt < 4; ++nt) {
          bf16x8 bb = *(const bf16x8*)(&lW[(nt * 16 + c) * WPITCH + kt * 32 + q * 8]);
          acc[0][nt] = __builtin_amdgcn_mfma_f32_16x16x32_bf16(a0, bb, acc[0][nt], 0, 0, 0);
          acc[1][nt] = __builtin_amdgcn_mfma_f32_16x16x32_bf16(a1, bb, acc[1][nt], 0, 0, 0);
        }
      }

#pragma unroll
      for (int mt = 0; mt < 2; ++mt) {
        float p0 = 0.f, p1 = 0.f, p2 = 0.f, p3 = 0.f;
#pragma unroll
        for (int nt = 0; nt < 4; ++nt) {
          p0 += fmaxf(acc[mt][nt][0] + b2v[nt], 0.f) * w3v[nt];
          p1 += fmaxf(acc[mt][nt][1] + b2v[nt], 0.f) * w3v[nt];
          p2 += fmaxf(acc[mt][nt][2] + b2v[nt], 0.f) * w3v[nt];
          p3 += fmaxf(acc[mt][nt][3] + b2v[nt], 0.f) * w3v[nt];
        }
#pragma unroll
        for (int m = 1; m < 16; m <<= 1) {
          p0 += __shfl_xor(p0, m, 64);
          p1 += __shfl_xor(p1, m, 64);
          p2 += __shfl_xor(p2, m, 64);
          p3 += __shfl_xor(p3, m, 64);
        }
        if (c == 0) {
          int eb = ebase + mt * 16 + q * 4;
          if (eb + 0 < NEDGE) out[eb + 0] = p0 + bias3;
          if (eb + 1 < NEDGE) out[eb + 1] = p1 + bias3;
          if (eb + 2 < NEDGE) out[eb + 2] = p2 + bias3;
          if (eb + 3 < NEDGE) out[eb + 3] = p3 + bias3;
        }
      }
    }
  }
}

extern "C" void kernel_launch(void* const* d_in, const int* in_sizes, int n_in,
                              void* d_out, int out_size, void* d_ws, size_t ws_size,
                              hipStream_t stream) {
  const float* z  = (const float*)d_in[0];
  const int*   ei = (const int*)d_in[1];
  const float* W1 = (const float*)d_in[2];
  const float* b1 = (const float*)d_in[3];
  const float* W2 = (const float*)d_in[4];
  const float* b2 = (const float*)d_in[5];
  const float* W3 = (const float*)d_in[6];
  const float* b3 = (const float*)d_in[7];
  float* out = (float*)d_out;

  unsigned short* UV    = (unsigned short*)d_ws;       // 50000*256 bf16 = 25.6 MB
  unsigned short* WcatT = UV + (size_t)NNODE * 256;    // 256*128 bf16
  unsigned short* W2T   = WcatT + 256 * 128;           // 64*128 bf16
  int* idx64_flag       = (int*)(W2T + 64 * 128);

  int maxB = 0;
  hipOccupancyMaxActiveBlocksPerMultiprocessor(&maxB, (const void*)fused_kernel, 256, 0);
  if (maxB < 1) maxB = 1;
  if (maxB > 8) maxB = 8;
  int grid = maxB * 256;

  void* args[] = {(void*)&z, (void*)&ei, (void*)&W1, (void*)&b1,
                  (void*)&W2, (void*)&b2, (void*)&W3, (void*)&b3,
                  (void*)&UV, (void*)&WcatT, (void*)&W2T, (void*)&idx64_flag,
                  (void*)&out};
  hipLaunchCooperativeKernel((const void*)fused_kernel, dim3(grid), dim3(256),
                             args, 0, stream);
}